// Round 1
// 449.814 us; speedup vs baseline: 1.1105x; 1.1105x over previous
//
#include <hip/hip_runtime.h>
#include <math.h>

// ---------------------------------------------------------------------------
// InfoNCE on MI355X — v4.
// T1[i,j] = tail(relu(hx[j]+hy[i]+b1)) = fused GEMM M=262144, N=512, K=512,
// A formed on the fly.
// v4 vs v3: 2-product precision scheme — A rounded to plain bf16 (its rounding
// error is i.i.d. per (i,j,k) and averages out through W3-dot/LSE/mean), B kept
// hi/lo split (weights stay accurate to ~2^-18). Drops 1/3 of MFMA work AND
// halves the A LDS traffic (single Ah buffer, 8 ds_read_b128/wave/k-step),
// which was serializing against the MFMA phase at 1 block/CU occupancy.
// Also: staging write map sm=t&127/seg=t>>7 (bank-group stride 5, balanced
// per quarter-wave) and s_setprio(1) around the MFMA cluster.
// ---------------------------------------------------------------------------

typedef __bf16 bf16x8 __attribute__((ext_vector_type(8)));
typedef float  f32x4  __attribute__((ext_vector_type(4)));

#define H    512
#define NPTS 512
#define XD   128
#define SP   40   // LDS row stride (elems) for 32-k chunk: 80B -> balanced banks

// ---------------- prep: hx, hy(+b1); W2 -> fragment-major bf16 hi/lo ------
__global__ __launch_bounds__(256) void prep_kernel(
    const float* __restrict__ x, const float* __restrict__ y,
    const float* __restrict__ W1x, const float* __restrict__ W1y,
    const float* __restrict__ b1, const float* __restrict__ W2,
    float* __restrict__ hx, float* __restrict__ hy,
    __bf16* __restrict__ w2h, __bf16* __restrict__ w2l) {
  __shared__ float xr[XD];
  const int b = blockIdx.x;
  const int t = threadIdx.x;
  if (b < 2 * NPTS) {
    const bool isY = (b >= NPTS);
    const int row = isY ? b - NPTS : b;
    const float* src = isY ? y : x;      // [NPTS][XD]
    const float* W   = isY ? W1y : W1x;  // [XD][H]
    if (t < XD) xr[t] = src[row * XD + t];
    __syncthreads();
    for (int c = t; c < H; c += 256) {
      float s = 0.f;
#pragma unroll
      for (int k = 0; k < XD; ++k) s = fmaf(xr[k], W[k * H + c], s);
      if (isY) hy[row * H + c] = s + b1[c];   // fold b1 into hy
      else     hx[row * H + c] = s;
    }
  } else {
    // W2[k][n] -> fragment-major: idx = ((n>>4)*16 + (k>>5))*512
    //                                   + (n&15)*32 + (k&31)
    // a wave's B-frag load (16 cols x 4 quads x 8 elems) = 1 KB contiguous.
    const int n = b - 2 * NPTS;
    for (int k = t; k < H; k += 256) {
      float v = W2[k * H + n];
      __bf16 hi = (__bf16)v;
      float lo = v - (float)hi;
      const int idx = (((n >> 4) * 16) + (k >> 5)) * 512 + (n & 15) * 32 + (k & 31);
      w2h[idx] = hi;
      w2l[idx] = (__bf16)lo;
    }
  }
}

// ---------------- pair GEMM + fused tail -> T1 (post-softplus) ------------
// grid 2048 = 32 i-groups x 64 j-groups; M-tile = 128 pairs (16 i x 8 j).
// 512 threads = 8 waves; wave w: all 128 rows x cols [w*64, w*64+64)
// (8 m-tiles x 4 n-tiles, acc[8][4]). K in 16 steps of 32, LDS double-buffer.
// 2 MFMA products per (tm,tn): A(bf16) x Bh + A(bf16) x Bl.
__global__ __launch_bounds__(512, 2) void pair_kernel(
    const float* __restrict__ hx, const float* __restrict__ hy,
    const __bf16* __restrict__ w2h, const __bf16* __restrict__ w2l,
    const float* __restrict__ b2, const float* __restrict__ W3,
    const float* __restrict__ b3, float* __restrict__ T1) {
  __shared__ __align__(16) __bf16 Ah[2][128 * SP];
  __shared__ float red[8][128];

  const int t    = threadIdx.x;
  const int i0   = (blockIdx.x >> 6) * 16;
  const int j0   = (blockIdx.x & 63) * 8;
  const int wave = t >> 6;
  const int lane = t & 63;
  const int col  = lane & 15;
  const int quad = lane >> 4;

  // staging: row sm (0..127), k-seg seg (8 elems of the 32-k chunk).
  // sm = t&127 so a wave's 64 writes walk rows consecutively: LDS bank-group
  // (5*sm+seg) mod 8 is balanced within every 16-lane quarter (stride 5).
  const int sm  = t & 127;
  const int seg = t >> 7;
  const float* hxp = hx + (j0 + (sm & 7)) * H + seg * 8;   // tj = sm&7
  const float* hyp = hy + (i0 + (sm >> 3)) * H + seg * 8;  // ti = sm>>3
  const int awoff = sm * SP + seg * 8;

  const int boff = col * 32 + quad * 8;   // lane offset inside 1KB B-frag
  const int g0   = wave * 4;              // B n-group base (n>>4)

  f32x4 acc[8][4] = {};
  bf16x8 Bh[2][4], Bl[2][4];

  auto stage = [&](int buf, float4 X0, float4 X1, float4 Y0, float4 Y1) {
    float a[8] = {X0.x + Y0.x, X0.y + Y0.y, X0.z + Y0.z, X0.w + Y0.w,
                  X1.x + Y1.x, X1.y + Y1.y, X1.z + Y1.z, X1.w + Y1.w};
    bf16x8 hv;
#pragma unroll
    for (int e = 0; e < 8; ++e) {
      float v = a[e] > 0.f ? a[e] : 0.f;   // first relu
      hv[e] = (__bf16)v;
    }
    *(bf16x8*)(&Ah[buf][awoff]) = hv;
  };

  // prologue: stage k-step 0, preload B for k-step 0
  {
    float4 x0 = *(const float4*)(hxp);
    float4 x1 = *(const float4*)(hxp + 4);
    float4 y0 = *(const float4*)(hyp);
    float4 y1 = *(const float4*)(hyp + 4);
    stage(0, x0, x1, y0, y1);
  }
#pragma unroll
  for (int tn = 0; tn < 4; ++tn) {
    const int base = ((g0 + tn) * 16) * 512 + boff;
    Bh[0][tn] = *(const bf16x8*)(w2h + base);
    Bl[0][tn] = *(const bf16x8*)(w2l + base);
  }
  __syncthreads();

#pragma unroll 2
  for (int ks = 0; ks < 16; ++ks) {
    const int cur = ks & 1;
    // prefetch staging loads for k-step ks+1 (consumed after MFMA phase)
    float4 nx0, nx1, ny0, ny1;
    if (ks < 15) {
      const float* px = hxp + (ks + 1) * 32;
      const float* py = hyp + (ks + 1) * 32;
      nx0 = *(const float4*)px; nx1 = *(const float4*)(px + 4);
      ny0 = *(const float4*)py; ny1 = *(const float4*)(py + 4);
    }
    // prefetch B frags for k-step ks+1 (used after next barrier)
    if (ks < 15) {
#pragma unroll
      for (int tn = 0; tn < 4; ++tn) {
        const int base = (((g0 + tn) * 16) + (ks + 1)) * 512 + boff;
        Bh[cur ^ 1][tn] = *(const bf16x8*)(w2h + base);
        Bl[cur ^ 1][tn] = *(const bf16x8*)(w2l + base);
      }
    }
    // MFMA phase: 8 m-tiles x 4 n-tiles x 2 products with B[cur]
    __builtin_amdgcn_s_setprio(1);
#pragma unroll
    for (int tm = 0; tm < 8; ++tm) {
      const int off = (tm * 16 + col) * SP + quad * 8;
      bf16x8 Af = *(const bf16x8*)(&Ah[cur][off]);
#pragma unroll
      for (int tn = 0; tn < 4; ++tn) {
        acc[tm][tn] = __builtin_amdgcn_mfma_f32_16x16x32_bf16(Af, Bh[cur][tn], acc[tm][tn], 0, 0, 0);
        acc[tm][tn] = __builtin_amdgcn_mfma_f32_16x16x32_bf16(Af, Bl[cur][tn], acc[tm][tn], 0, 0, 0);
      }
    }
    __builtin_amdgcn_s_setprio(0);
    // write next chunk into the other LDS buffer (readers synced 1 barrier ago)
    if (ks < 15) stage(cur ^ 1, nx0, nx1, ny0, ny1);
    __syncthreads();
  }

  // epilogue: v = relu(h2 + b2); p = v*W3; reduce over 16 col-lanes; softplus
  float bb[4], w3v[4];
#pragma unroll
  for (int tn = 0; tn < 4; ++tn) {
    const int n = wave * 64 + tn * 16 + col;
    bb[tn]  = b2[n];
    w3v[tn] = W3[n];
  }
#pragma unroll
  for (int tm = 0; tm < 8; ++tm) {
#pragma unroll
    for (int reg = 0; reg < 4; ++reg) {
      float p = 0.f;
#pragma unroll
      for (int tn = 0; tn < 4; ++tn) {
        float v = acc[tm][tn][reg] + bb[tn];
        v = v > 0.f ? v : 0.f;               // second relu
        p = fmaf(v, w3v[tn], p);
      }
      p += __shfl_xor(p, 1);
      p += __shfl_xor(p, 2);
      p += __shfl_xor(p, 4);
      p += __shfl_xor(p, 8);
      if (col == 0) red[wave][tm * 16 + quad * 4 + reg] = p;
    }
  }
  __syncthreads();
  if (t < 128) {
    float s = b3[0];
#pragma unroll
    for (int w = 0; w < 8; ++w) s += red[w][t];
    const float sp = s > 0.f ? s + log1pf(expf(-s)) : log1pf(expf(s));
    const int ti = t >> 3, tj = t & 7;
    T1[(i0 + ti) * NPTS + (j0 + tj)] = sp;   // row = i (hy), col = j (hx)
  }
}

// ---------------- parallel lse: one wave per row --------------------------
__global__ __launch_bounds__(512) void rowlse_kernel(
    const float* __restrict__ T1, float* __restrict__ lse) {
  const int r    = blockIdx.x * 8 + (threadIdx.x >> 6);
  const int lane = threadIdx.x & 63;
  const float* row = T1 + r * NPTS;
  float se = 0.f;
#pragma unroll
  for (int q = 0; q < 8; ++q) se += expf(row[lane + q * 64]);
#pragma unroll
  for (int off = 1; off < 64; off <<= 1) se += __shfl_xor(se, off);
  if (lane == 0) lse[r] = logf(se);
}

// ---------------- final: mean(diag) - (mean(lse) - log N) -----------------
__global__ __launch_bounds__(512) void final_kernel(
    const float* __restrict__ T1, const float* __restrict__ lse,
    float* __restrict__ out) {
  __shared__ float s1[8], s2[8];
  const int t = threadIdx.x, lane = t & 63, w = t >> 6;
  float a = T1[t * NPTS + t];   // diag == T0
  float b = lse[t];
#pragma unroll
  for (int off = 1; off < 64; off <<= 1) {
    a += __shfl_xor(a, off);
    b += __shfl_xor(b, off);
  }
  if (lane == 0) { s1[w] = a; s2[w] = b; }
  __syncthreads();
  if (t == 0) {
    float sa = 0.f, sb = 0.f;
#pragma unroll
    for (int i = 0; i < 8; ++i) { sa += s1[i]; sb += s2[i]; }
    out[0] = sa / 512.0f - sb / 512.0f + logf(512.0f);
  }
}

// ---------------------------------------------------------------------------
extern "C" void kernel_launch(void* const* d_in, const int* in_sizes, int n_in,
                              void* d_out, int out_size, void* d_ws, size_t ws_size,
                              hipStream_t stream) {
  const float* x   = (const float*)d_in[0];
  const float* y   = (const float*)d_in[1];
  const float* W1x = (const float*)d_in[2];
  const float* W1y = (const float*)d_in[3];
  const float* b1  = (const float*)d_in[4];
  const float* W2  = (const float*)d_in[5];
  const float* b2  = (const float*)d_in[6];
  const float* W3  = (const float*)d_in[7];
  const float* b3  = (const float*)d_in[8];

  float* ws = (float*)d_ws;
  float* hx = ws;                         // 512*512 f32
  float* hy = ws + 262144;                // 512*512 f32
  float* T1 = ws + 524288;                // 512*512 f32
  __bf16* w2h = (__bf16*)(ws + 786432);   // 512*512 bf16 (fragment-major)
  __bf16* w2l = w2h + 262144;             // 512*512 bf16
  float* lse = ws + 786432 + 131072;      // 512 f32
  float* out = (float*)d_out;

  hipLaunchKernelGGL(prep_kernel, dim3(1536), dim3(256), 0, stream,
                     x, y, W1x, W1y, b1, W2, hx, hy, w2h, w2l);
  hipLaunchKernelGGL(pair_kernel, dim3(2048), dim3(512), 0, stream,
                     hx, hy, w2h, w2l, b2, W3, b3, T1);
  hipLaunchKernelGGL(rowlse_kernel, dim3(64), dim3(512), 0, stream, T1, lse);
  hipLaunchKernelGGL(final_kernel, dim3(1), dim3(512), 0, stream, T1, lse, out);
}

// Round 2
// 445.603 us; speedup vs baseline: 1.1210x; 1.0095x over previous
//
#include <hip/hip_runtime.h>
#include <math.h>

// ---------------------------------------------------------------------------
// InfoNCE on MI355X — v5.
// T1[i,j] = tail(relu(hx[j]+hy[i]+b1)) = fused GEMM M=262144, N=512, K=512,
// A formed on the fly; 2 MFMA products (A bf16, B hi/lo split).
// v5 vs v4: BARRIER-FREE K-LOOP. The full A-tile (128 rows x 512 K bf16 =
// 130 KB, stride-520 rows for bank uniformity) is staged into dynamic LDS
// ONCE, then the 16 k-steps run with no __syncthreads, no ds_writes, no
// vmcnt/lgkmcnt drains. Waves de-synchronize, so MFMA clusters of one wave
// hide B-loads/ds_reads of the other (setprio now has a role-split to
// arbitrate). v4 was pinned at the known 2-barrier structural ceiling
// (MfmaUtil 37%); this removes the structure instead of tuning it.
// ---------------------------------------------------------------------------

typedef __bf16 bf16x8 __attribute__((ext_vector_type(8)));
typedef float  f32x4  __attribute__((ext_vector_type(4)));

#define H    512
#define NPTS 512
#define XD   128
#define SPA  520   // full-K LDS row stride (elems): 1040 B -> rows walk bank
                   // groups at stride 1 (65 granules), uniform for b128 r/w

// ---------------- prep: hx, hy(+b1); W2 -> fragment-major bf16 hi/lo ------
__global__ __launch_bounds__(256) void prep_kernel(
    const float* __restrict__ x, const float* __restrict__ y,
    const float* __restrict__ W1x, const float* __restrict__ W1y,
    const float* __restrict__ b1, const float* __restrict__ W2,
    float* __restrict__ hx, float* __restrict__ hy,
    __bf16* __restrict__ w2h, __bf16* __restrict__ w2l) {
  __shared__ float xr[XD];
  const int b = blockIdx.x;
  const int t = threadIdx.x;
  if (b < 2 * NPTS) {
    const bool isY = (b >= NPTS);
    const int row = isY ? b - NPTS : b;
    const float* src = isY ? y : x;      // [NPTS][XD]
    const float* W   = isY ? W1y : W1x;  // [XD][H]
    if (t < XD) xr[t] = src[row * XD + t];
    __syncthreads();
    for (int c = t; c < H; c += 256) {
      float s = 0.f;
#pragma unroll
      for (int k = 0; k < XD; ++k) s = fmaf(xr[k], W[k * H + c], s);
      if (isY) hy[row * H + c] = s + b1[c];   // fold b1 into hy
      else     hx[row * H + c] = s;
    }
  } else {
    // W2[k][n] -> fragment-major: idx = ((n>>4)*16 + (k>>5))*512
    //                                   + (n&15)*32 + (k&31)
    // a wave's B-frag load (16 cols x 4 quads x 8 elems) = 1 KB contiguous.
    const int n = b - 2 * NPTS;
    for (int k = t; k < H; k += 256) {
      float v = W2[k * H + n];
      __bf16 hi = (__bf16)v;
      float lo = v - (float)hi;
      const int idx = (((n >> 4) * 16) + (k >> 5)) * 512 + (n & 15) * 32 + (k & 31);
      w2h[idx] = hi;
      w2l[idx] = (__bf16)lo;
    }
  }
}

// ---------------- pair GEMM + fused tail -> T1 (post-softplus) ------------
// grid 2048 = 32 i-groups x 64 j-groups; M-tile = 128 pairs (16 i x 8 j).
// 512 threads = 8 waves; wave w: all 128 rows x cols [w*64, w*64+64)
// (8 m-tiles x 4 n-tiles, acc[8][4]). A staged once (full K) in dynamic LDS;
// K-loop is barrier-free. 2 MFMA products per (tm,tn): A x Bh + A x Bl.
__global__ __launch_bounds__(512, 2) void pair_kernel(
    const float* __restrict__ hx, const float* __restrict__ hy,
    const __bf16* __restrict__ w2h, const __bf16* __restrict__ w2l,
    const float* __restrict__ b2, const float* __restrict__ W3,
    const float* __restrict__ b3, float* __restrict__ T1) {
  extern __shared__ __align__(16) __bf16 Ah[];   // [128][SPA] = 130 KB
  __shared__ float red[8][128];

  const int t    = threadIdx.x;
  const int i0   = (blockIdx.x >> 6) * 16;
  const int j0   = (blockIdx.x & 63) * 8;
  const int wave = t >> 6;
  const int lane = t & 63;
  const int col  = lane & 15;
  const int quad = lane >> 4;

  // ---- upfront staging of the whole 128 x 512 A tile -----------------
  // 4 threads per row; thread covers 16 of the 64 8-elem segments.
  // write bank-quad = (row + seg) mod 8 -> uniform across each wave.
  {
    const int sm = t & 127;
    const int s0 = t >> 7;
    const float* hxp = hx + (j0 + (sm & 7)) * H;   // tj = sm&7
    const float* hyp = hy + (i0 + (sm >> 3)) * H;  // ti = sm>>3
#pragma unroll 4
    for (int c = 0; c < 16; ++c) {
      const int seg = s0 + c * 4;
      const int k   = seg * 8;
      float4 x0 = *(const float4*)(hxp + k);
      float4 x1 = *(const float4*)(hxp + k + 4);
      float4 y0 = *(const float4*)(hyp + k);
      float4 y1 = *(const float4*)(hyp + k + 4);
      float a[8] = {x0.x + y0.x, x0.y + y0.y, x0.z + y0.z, x0.w + y0.w,
                    x1.x + y1.x, x1.y + y1.y, x1.z + y1.z, x1.w + y1.w};
      bf16x8 hv;
#pragma unroll
      for (int e = 0; e < 8; ++e) {
        float v = a[e] > 0.f ? a[e] : 0.f;   // first relu
        hv[e] = (__bf16)v;
      }
      *(bf16x8*)(&Ah[sm * SPA + k]) = hv;
    }
  }

  const int boff = col * 32 + quad * 8;   // lane offset inside 1KB B-frag
  const int g0   = wave * 4;              // B n-group base (n>>4)

  f32x4 acc[8][4] = {};
  bf16x8 Bh[2][4], Bl[2][4];

  // preload B for k-step 0
#pragma unroll
  for (int tn = 0; tn < 4; ++tn) {
    const int base = ((g0 + tn) * 16) * 512 + boff;
    Bh[0][tn] = *(const bf16x8*)(w2h + base);
    Bl[0][tn] = *(const bf16x8*)(w2l + base);
  }
  __syncthreads();   // the ONLY barrier before the epilogue

  // ---- barrier-free K-loop: 16 steps of 32 ---------------------------
#pragma unroll 2
  for (int ks = 0; ks < 16; ++ks) {
    const int cur = ks & 1;
    // prefetch B frags for k-step ks+1 (counted vmcnt by compiler; no
    // barrier ever drains them)
    if (ks < 15) {
#pragma unroll
      for (int tn = 0; tn < 4; ++tn) {
        const int base = (((g0 + tn) * 16) + (ks + 1)) * 512 + boff;
        Bh[cur ^ 1][tn] = *(const bf16x8*)(w2h + base);
        Bl[cur ^ 1][tn] = *(const bf16x8*)(w2l + base);
      }
    }
    // MFMA phase: 8 m-tiles x 4 n-tiles x 2 products with B[cur]
    __builtin_amdgcn_s_setprio(1);
#pragma unroll
    for (int tm = 0; tm < 8; ++tm) {
      const int off = (tm * 16 + col) * SPA + ks * 32 + quad * 8;
      bf16x8 Af = *(const bf16x8*)(&Ah[off]);
#pragma unroll
      for (int tn = 0; tn < 4; ++tn) {
        acc[tm][tn] = __builtin_amdgcn_mfma_f32_16x16x32_bf16(Af, Bh[cur][tn], acc[tm][tn], 0, 0, 0);
        acc[tm][tn] = __builtin_amdgcn_mfma_f32_16x16x32_bf16(Af, Bl[cur][tn], acc[tm][tn], 0, 0, 0);
      }
    }
    __builtin_amdgcn_s_setprio(0);
  }

  // epilogue: v = relu(h2 + b2); p = v*W3; reduce over 16 col-lanes; softplus
  float bb[4], w3v[4];
#pragma unroll
  for (int tn = 0; tn < 4; ++tn) {
    const int n = wave * 64 + tn * 16 + col;
    bb[tn]  = b2[n];
    w3v[tn] = W3[n];
  }
#pragma unroll
  for (int tm = 0; tm < 8; ++tm) {
#pragma unroll
    for (int reg = 0; reg < 4; ++reg) {
      float p = 0.f;
#pragma unroll
      for (int tn = 0; tn < 4; ++tn) {
        float v = acc[tm][tn][reg] + bb[tn];
        v = v > 0.f ? v : 0.f;               // second relu
        p = fmaf(v, w3v[tn], p);
      }
      p += __shfl_xor(p, 1);
      p += __shfl_xor(p, 2);
      p += __shfl_xor(p, 4);
      p += __shfl_xor(p, 8);
      if (col == 0) red[wave][tm * 16 + quad * 4 + reg] = p;
    }
  }
  __syncthreads();
  if (t < 128) {
    float s = b3[0];
#pragma unroll
    for (int w = 0; w < 8; ++w) s += red[w][t];
    const float sp = s > 0.f ? s + log1pf(expf(-s)) : log1pf(expf(s));
    const int ti = t >> 3, tj = t & 7;
    T1[(i0 + ti) * NPTS + (j0 + tj)] = sp;   // row = i (hy), col = j (hx)
  }
}

// ---------------- parallel lse: one wave per row --------------------------
__global__ __launch_bounds__(512) void rowlse_kernel(
    const float* __restrict__ T1, float* __restrict__ lse) {
  const int r    = blockIdx.x * 8 + (threadIdx.x >> 6);
  const int lane = threadIdx.x & 63;
  const float* row = T1 + r * NPTS;
  float se = 0.f;
#pragma unroll
  for (int q = 0; q < 8; ++q) se += expf(row[lane + q * 64]);
#pragma unroll
  for (int off = 1; off < 64; off <<= 1) se += __shfl_xor(se, off);
  if (lane == 0) lse[r] = logf(se);
}

// ---------------- final: mean(diag) - (mean(lse) - log N) -----------------
__global__ __launch_bounds__(512) void final_kernel(
    const float* __restrict__ T1, const float* __restrict__ lse,
    float* __restrict__ out) {
  __shared__ float s1[8], s2[8];
  const int t = threadIdx.x, lane = t & 63, w = t >> 6;
  float a = T1[t * NPTS + t];   // diag == T0
  float b = lse[t];
#pragma unroll
  for (int off = 1; off < 64; off <<= 1) {
    a += __shfl_xor(a, off);
    b += __shfl_xor(b, off);
  }
  if (lane == 0) { s1[w] = a; s2[w] = b; }
  __syncthreads();
  if (t == 0) {
    float sa = 0.f, sb = 0.f;
#pragma unroll
    for (int i = 0; i < 8; ++i) { sa += s1[i]; sb += s2[i]; }
    out[0] = sa / 512.0f - sb / 512.0f + logf(512.0f);
  }
}

// ---------------------------------------------------------------------------
extern "C" void kernel_launch(void* const* d_in, const int* in_sizes, int n_in,
                              void* d_out, int out_size, void* d_ws, size_t ws_size,
                              hipStream_t stream) {
  const float* x   = (const float*)d_in[0];
  const float* y   = (const float*)d_in[1];
  const float* W1x = (const float*)d_in[2];
  const float* W1y = (const float*)d_in[3];
  const float* b1  = (const float*)d_in[4];
  const float* W2  = (const float*)d_in[5];
  const float* b2  = (const float*)d_in[6];
  const float* W3  = (const float*)d_in[7];
  const float* b3  = (const float*)d_in[8];

  float* ws = (float*)d_ws;
  float* hx = ws;                         // 512*512 f32
  float* hy = ws + 262144;                // 512*512 f32
  float* T1 = ws + 524288;                // 512*512 f32
  __bf16* w2h = (__bf16*)(ws + 786432);   // 512*512 bf16 (fragment-major)
  __bf16* w2l = w2h + 262144;             // 512*512 bf16
  float* lse = ws + 786432 + 131072;      // 512 f32
  float* out = (float*)d_out;

  // dynamic LDS: 128 rows x SPA(520) x 2B = 133120 B (>64 KB default cap)
  static bool configured = false;
  if (!configured) {
    hipFuncSetAttribute(reinterpret_cast<const void*>(pair_kernel),
                        hipFuncAttributeMaxDynamicSharedMemorySize,
                        128 * SPA * 2);
    configured = true;
  }

  hipLaunchKernelGGL(prep_kernel, dim3(1536), dim3(256), 0, stream,
                     x, y, W1x, W1y, b1, W2, hx, hy, w2h, w2l);
  hipLaunchKernelGGL(pair_kernel, dim3(2048), dim3(512), 128 * SPA * 2, stream,
                     hx, hy, w2h, w2l, b2, W3, b3, T1);
  hipLaunchKernelGGL(rowlse_kernel, dim3(64), dim3(512), 0, stream, T1, lse);
  hipLaunchKernelGGL(final_kernel, dim3(1), dim3(512), 0, stream, T1, lse, out);
}

// Round 3
// 429.582 us; speedup vs baseline: 1.1628x; 1.0373x over previous
//
#include <hip/hip_runtime.h>
#include <math.h>

// ---------------------------------------------------------------------------
// InfoNCE on MI355X — v6.
// T1[i,j] = tail(relu(hx[j]+hy[i]+b1)) = fused GEMM M=262144, N=512, K=512,
// A formed on the fly; 2 MFMA products (A bf16, B hi/lo split).
// v6 vs v5: occupancy + MFMA-rate attack. v5 was stuck at 42% of dense: 2
// waves/SIMD (240 regs/wave) phase-couple on the shared matrix pipe. v6:
// 1024 threads / 16 waves, wave tile 128x32 (acc 64 regs), 32x32x16 MFMA
// (2495 vs 2075 TF rate, 4x fewer instructions), single-n-group B frags
// (16 regs, half-step double-buffer) -> ~115 regs/wave, launch_bounds
// (1024,4) forces 4 waves/SIMD. Barrier-free K-loop retained (A staged
// once, full K, in 133 KB dynamic LDS). Epilogue: 2-stage shfl + partials
// into LDS aliased over the dead A tile.
// ---------------------------------------------------------------------------

typedef __bf16 bf16x8 __attribute__((ext_vector_type(8)));
typedef float  f32x16 __attribute__((ext_vector_type(16)));

#define H    512
#define NPTS 512
#define XD   128
#define SPA  520   // A-tile LDS row stride (elems): 1040 B, bank-uniform
#define PLS  132   // epilogue partial-scratch row stride (f32)

// ---------------- prep: hx, hy(+b1); W2 -> fragment-major bf16 hi/lo ------
__global__ __launch_bounds__(256) void prep_kernel(
    const float* __restrict__ x, const float* __restrict__ y,
    const float* __restrict__ W1x, const float* __restrict__ W1y,
    const float* __restrict__ b1, const float* __restrict__ W2,
    float* __restrict__ hx, float* __restrict__ hy,
    __bf16* __restrict__ w2h, __bf16* __restrict__ w2l) {
  __shared__ float xr[XD];
  const int b = blockIdx.x;
  const int t = threadIdx.x;
  if (b < 2 * NPTS) {
    const bool isY = (b >= NPTS);
    const int row = isY ? b - NPTS : b;
    const float* src = isY ? y : x;      // [NPTS][XD]
    const float* W   = isY ? W1y : W1x;  // [XD][H]
    if (t < XD) xr[t] = src[row * XD + t];
    __syncthreads();
    for (int c = t; c < H; c += 256) {
      float s = 0.f;
#pragma unroll
      for (int k = 0; k < XD; ++k) s = fmaf(xr[k], W[k * H + c], s);
      if (isY) hy[row * H + c] = s + b1[c];   // fold b1 into hy
      else     hx[row * H + c] = s;
    }
  } else {
    // W2[k][n] -> 32x32x16-fragment-major:
    // idx = ((n>>5)*32 + (k>>4))*512 + (n&31)*16 + (k&15)
    // one wave's B-frag (32 cols x 16 k) = 1 KB contiguous; lane l holds
    // col = l&31, k = (l>>5)*8 + e.
    const int n = b - 2 * NPTS;
    for (int k = t; k < H; k += 256) {
      float v = W2[k * H + n];
      __bf16 hi = (__bf16)v;
      float lo = v - (float)hi;
      const int idx = (((n >> 5) * 32) + (k >> 4)) * 512 + (n & 31) * 16 + (k & 15);
      w2h[idx] = hi;
      w2l[idx] = (__bf16)lo;
    }
  }
}

// ---------------- pair GEMM + fused tail -> T1 (post-softplus) ------------
// grid 2048 = 32 i-groups x 64 j-groups; M-tile = 128 pairs (16 i x 8 j).
// 1024 threads = 16 waves; wave w: all 128 rows x cols [w*32, w*32+32)
// (4 m-tiles of 32 rows, 1 n-group; acc[4] of f32x16). K in 32 half-steps
// of 16; B half-step double-buffered in 16 regs; no barrier in the K-loop.
__global__ __launch_bounds__(1024, 4) void pair_kernel(
    const float* __restrict__ hx, const float* __restrict__ hy,
    const __bf16* __restrict__ w2h, const __bf16* __restrict__ w2l,
    const float* __restrict__ b2, const float* __restrict__ W3,
    const float* __restrict__ b3, float* __restrict__ T1) {
  extern __shared__ __align__(16) __bf16 Ah[];   // [128][SPA] = 133120 B

  const int t    = threadIdx.x;
  const int i0   = (blockIdx.x >> 6) * 16;
  const int j0   = (blockIdx.x & 63) * 8;
  const int wave = t >> 6;
  const int lane = t & 63;
  const int r31  = lane & 31;
  const int half = lane >> 5;

  // B frag pointers: wave w owns n-group w (cols w*32..w*32+31).
  // group index for K-half hs is (w*32 + hs); lane offset inside the 1KB frag.
  const int boff = r31 * 16 + half * 8;
  const __bf16* w2hW = w2h + wave * (32 * 512) + boff;
  const __bf16* w2lW = w2l + wave * (32 * 512) + boff;

  // prologue B loads for half 0 (issued before staging; land during it)
  bf16x8 Bhb[2], Blb[2];
  Bhb[0] = *(const bf16x8*)(w2hW);
  Blb[0] = *(const bf16x8*)(w2lW);

  // ---- upfront staging of the whole 128 x 512 A tile -----------------
  // 8 threads per row, 8 segs (of 8 elems) per thread.
  {
    const int sm = t >> 3;        // pair row 0..127  (ti = sm>>3, tj = sm&7)
    const int sl = t & 7;
    const float* hxp = hx + (j0 + (sm & 7)) * H;
    const float* hyp = hy + (i0 + (sm >> 3)) * H;
    __bf16* arow = Ah + sm * SPA;
#pragma unroll
    for (int c = 0; c < 8; ++c) {
      const int k = sl * 8 + c * 64;
      float4 x0 = *(const float4*)(hxp + k);
      float4 x1 = *(const float4*)(hxp + k + 4);
      float4 y0 = *(const float4*)(hyp + k);
      float4 y1 = *(const float4*)(hyp + k + 4);
      float a[8] = {x0.x + y0.x, x0.y + y0.y, x0.z + y0.z, x0.w + y0.w,
                    x1.x + y1.x, x1.y + y1.y, x1.z + y1.z, x1.w + y1.w};
      bf16x8 hv;
#pragma unroll
      for (int e = 0; e < 8; ++e) {
        float v = a[e] > 0.f ? a[e] : 0.f;   // first relu
        hv[e] = (__bf16)v;
      }
      *(bf16x8*)(&arow[k]) = hv;
    }
  }

  // A-frag LDS offsets (elems): row = mt*32 + r31, k-base = half*8; +hs*16/half
  int aoff[4];
#pragma unroll
  for (int mt = 0; mt < 4; ++mt) aoff[mt] = (mt * 32 + r31) * SPA + half * 8;

  f32x16 acc[4] = {};

  __syncthreads();   // staging complete; only barrier before epilogue

  // ---- barrier-free K-loop: 32 half-steps of K=16 --------------------
#pragma unroll
  for (int hs = 0; hs < 32; ++hs) {
    const int cur = hs & 1;
    if (hs < 31) {   // prefetch B for next half-step
      Bhb[cur ^ 1] = *(const bf16x8*)(w2hW + (hs + 1) * 512);
      Blb[cur ^ 1] = *(const bf16x8*)(w2lW + (hs + 1) * 512);
    }
    bf16x8 a0 = *(const bf16x8*)(Ah + aoff[0] + hs * 16);
    bf16x8 a1 = *(const bf16x8*)(Ah + aoff[1] + hs * 16);
    bf16x8 a2 = *(const bf16x8*)(Ah + aoff[2] + hs * 16);
    bf16x8 a3 = *(const bf16x8*)(Ah + aoff[3] + hs * 16);
    __builtin_amdgcn_s_setprio(1);
    acc[0] = __builtin_amdgcn_mfma_f32_32x32x16_bf16(a0, Bhb[cur], acc[0], 0, 0, 0);
    acc[1] = __builtin_amdgcn_mfma_f32_32x32x16_bf16(a1, Bhb[cur], acc[1], 0, 0, 0);
    acc[2] = __builtin_amdgcn_mfma_f32_32x32x16_bf16(a2, Bhb[cur], acc[2], 0, 0, 0);
    acc[3] = __builtin_amdgcn_mfma_f32_32x32x16_bf16(a3, Bhb[cur], acc[3], 0, 0, 0);
    acc[0] = __builtin_amdgcn_mfma_f32_32x32x16_bf16(a0, Blb[cur], acc[0], 0, 0, 0);
    acc[1] = __builtin_amdgcn_mfma_f32_32x32x16_bf16(a1, Blb[cur], acc[1], 0, 0, 0);
    acc[2] = __builtin_amdgcn_mfma_f32_32x32x16_bf16(a2, Blb[cur], acc[2], 0, 0, 0);
    acc[3] = __builtin_amdgcn_mfma_f32_32x32x16_bf16(a3, Blb[cur], acc[3], 0, 0, 0);
    __builtin_amdgcn_s_setprio(0);
  }

  __syncthreads();   // all waves done reading Ah -> safe to alias its LDS

  // epilogue: v = relu(h2 + b2); p = v*W3; 2-stage shfl (cols x4) ->
  // partials PL[row][128] in LDS (aliasing Ah), final 128-thread reduce.
  float* PL = (float*)Ah;            // [128][PLS]
  const int n = wave * 32 + r31;
  const float bb  = b2[n];
  const float w3v = W3[n];
  const int cg = wave * 8 + (r31 >> 2);   // col-group 0..127
#pragma unroll
  for (int mt = 0; mt < 4; ++mt) {
#pragma unroll
    for (int r = 0; r < 16; ++r) {
      float v = acc[mt][r] + bb;
      v = v > 0.f ? v : 0.f;               // second relu
      float p = v * w3v;
      p += __shfl_xor(p, 1);
      p += __shfl_xor(p, 2);
      if ((r31 & 3) == 0) {
        const int row = mt * 32 + (r & 3) + 8 * (r >> 2) + 4 * half;
        PL[row * PLS + cg] = p;
      }
    }
  }
  __syncthreads();
  if (t < 128) {
    float s = b3[0];
    const float* pr = PL + t * PLS;
#pragma unroll
    for (int c = 0; c < 32; ++c) {
      float4 q = *(const float4*)(pr + c * 4);
      s += q.x + q.y + q.z + q.w;
    }
    const float sp = s > 0.f ? s + log1pf(expf(-s)) : log1pf(expf(s));
    const int ti = t >> 3, tj = t & 7;
    T1[(i0 + ti) * NPTS + (j0 + tj)] = sp;   // row = i (hy), col = j (hx)
  }
}

// ---------------- parallel lse: one wave per row --------------------------
__global__ __launch_bounds__(512) void rowlse_kernel(
    const float* __restrict__ T1, float* __restrict__ lse) {
  const int r    = blockIdx.x * 8 + (threadIdx.x >> 6);
  const int lane = threadIdx.x & 63;
  const float* row = T1 + r * NPTS;
  float se = 0.f;
#pragma unroll
  for (int q = 0; q < 8; ++q) se += expf(row[lane + q * 64]);
#pragma unroll
  for (int off = 1; off < 64; off <<= 1) se += __shfl_xor(se, off);
  if (lane == 0) lse[r] = logf(se);
}

// ---------------- final: mean(diag) - (mean(lse) - log N) -----------------
__global__ __launch_bounds__(512) void final_kernel(
    const float* __restrict__ T1, const float* __restrict__ lse,
    float* __restrict__ out) {
  __shared__ float s1[8], s2[8];
  const int t = threadIdx.x, lane = t & 63, w = t >> 6;
  float a = T1[t * NPTS + t];   // diag == T0
  float b = lse[t];
#pragma unroll
  for (int off = 1; off < 64; off <<= 1) {
    a += __shfl_xor(a, off);
    b += __shfl_xor(b, off);
  }
  if (lane == 0) { s1[w] = a; s2[w] = b; }
  __syncthreads();
  if (t == 0) {
    float sa = 0.f, sb = 0.f;
#pragma unroll
    for (int i = 0; i < 8; ++i) { sa += s1[i]; sb += s2[i]; }
    out[0] = sa / 512.0f - sb / 512.0f + logf(512.0f);
  }
}

// ---------------------------------------------------------------------------
extern "C" void kernel_launch(void* const* d_in, const int* in_sizes, int n_in,
                              void* d_out, int out_size, void* d_ws, size_t ws_size,
                              hipStream_t stream) {
  const float* x   = (const float*)d_in[0];
  const float* y   = (const float*)d_in[1];
  const float* W1x = (const float*)d_in[2];
  const float* W1y = (const float*)d_in[3];
  const float* b1  = (const float*)d_in[4];
  const float* W2  = (const float*)d_in[5];
  const float* b2  = (const float*)d_in[6];
  const float* W3  = (const float*)d_in[7];
  const float* b3  = (const float*)d_in[8];

  float* ws = (float*)d_ws;
  float* hx = ws;                         // 512*512 f32
  float* hy = ws + 262144;                // 512*512 f32
  float* T1 = ws + 524288;                // 512*512 f32
  __bf16* w2h = (__bf16*)(ws + 786432);   // 512*512 bf16 (fragment-major)
  __bf16* w2l = w2h + 262144;             // 512*512 bf16
  float* lse = ws + 786432 + 131072;      // 512 f32
  float* out = (float*)d_out;

  // dynamic LDS: 128 rows x SPA(520) x 2B = 133120 B (>64 KB default cap)
  static bool configured = false;
  if (!configured) {
    hipFuncSetAttribute(reinterpret_cast<const void*>(pair_kernel),
                        hipFuncAttributeMaxDynamicSharedMemorySize,
                        128 * SPA * 2);
    configured = true;
  }

  hipLaunchKernelGGL(prep_kernel, dim3(1536), dim3(256), 0, stream,
                     x, y, W1x, W1y, b1, W2, hx, hy, w2h, w2l);
  hipLaunchKernelGGL(pair_kernel, dim3(2048), dim3(1024), 128 * SPA * 2, stream,
                     hx, hy, w2h, w2l, b2, W3, b3, T1);
  hipLaunchKernelGGL(rowlse_kernel, dim3(64), dim3(512), 0, stream, T1, lse);
  hipLaunchKernelGGL(final_kernel, dim3(1), dim3(512), 0, stream, T1, lse, out);
}